// Round 8
// baseline (281.164 us; speedup 1.0000x reference)
//
#include <hip/hip_runtime.h>
#include <hip/hip_bf16.h>

#define B_ 4096
#define D_ 32
#define H_ 1024
#define RW 8                   // batch rows per workgroup
#define ARW 40                 // LDS activation row stride (shorts): conflict-free, 16B-aligned
#define ACH (RW * ARW)         // activation chunk stride = 320 shorts
#define WPK_L 1079296          // shorts per hidden-layer weight pack (= 2048*sum(idx+1))

typedef __attribute__((ext_vector_type(8))) short short8;
typedef __attribute__((ext_vector_type(4))) float floatx4;

__device__ inline unsigned short f2bf(float f) {      // fp32 -> bf16 bits, RNE
    unsigned u = __float_as_uint(f);
    unsigned r = (u + 0x7FFF + ((u >> 16) & 1)) >> 16;
    return (unsigned short)r;
}

// degree-sorted order: degree 0 -> slots [0,34), degree d>=1 -> slots [33d+1, 33d+34)
__device__ inline int degs(int hp) { return (hp < 34) ? 0 : (hp - 1) / 33; }
__device__ inline int permf(int hp) {                  // sorted slot -> original h
    int d = degs(hp);
    int r = d ? (hp - 33 * d - 1) : hp;
    return d + 31 * r;
}
__device__ inline int band0(int idx) {                 // fresh-band base slot at step idx
    int nb0 = (idx == 1) ? 0 : 33 * idx - 32;
    return (nb0 > H_ - 64) ? H_ - 64 : nb0;
}

// ---- prep: hidden weights -> per-step band packs, B-frag order [chunk][slot64][32] ----
__global__ void pack_wh(const float* __restrict__ Wh, unsigned short* __restrict__ Wpk) {
    int b = blockIdx.x;                 // 2 layers * 31 idx * 32 max-chunks
    int l = b / 992;
    int r = b - l * 992;
    int idx = (r >> 5) + 1;
    int c = r & 31;
    if (c >= idx + 1) return;           // nk(idx) = idx+1 chunks
    int nb0 = band0(idx);
    size_t off = (size_t)l * WPK_L + (size_t)1024 * (idx - 1) * (idx + 2) + c * 2048;
    int t = threadIdx.x;
    int j = t >> 2, ko = (t & 3) * 8;
    int n = nb0 + j;
    int dn = degs(n);
    const float* srow = Wh + ((size_t)l << 20) + ((size_t)permf(n) << 10);
    union { unsigned short o[8]; uint4 v; } u;
    #pragma unroll
    for (int e = 0; e < 8; e++) {
        int k = c * 32 + ko + e;
        u.o[e] = (dn >= degs(k)) ? f2bf(srow[permf(k)]) : (unsigned short)0;
    }
    *(uint4*)(Wpk + off + j * 32 + ko) = u.v;
}

// ---- prep (fused): W0 packs, Wout packs, biases ----
__global__ void pack_misc(const float* __restrict__ W0, const float* __restrict__ Wout,
                          const float* __restrict__ b0, const float* __restrict__ bh,
                          unsigned short* __restrict__ W0pk, unsigned short* __restrict__ Wopk,
                          float* __restrict__ b0p, float* __restrict__ bhp) {
    int b = blockIdx.x;
    int t = threadIdx.x;
    if (b < 31) {                       // W0 band pack, idx = b+1: [idx][slot64][32]
        int idx = b + 1;
        int nb0 = band0(idx);
        int j = t >> 2, ko = (t & 3) * 8;
        int n = nb0 + j;
        int dn = degs(n);
        const float* srow = W0 + (size_t)permf(n) * 32;
        union { unsigned short o[8]; uint4 v; } u;
        #pragma unroll
        for (int e = 0; e < 8; e++)
            u.o[e] = (dn >= ko + e) ? f2bf(srow[ko + e]) : (unsigned short)0;
        *(uint4*)(W0pk + (idx - 1) * 2048 + j * 32 + ko) = u.v;
    } else if (b < 31 + 1024) {         // Wout packs [idx][chunk32][col16][32]
        int bb = b - 31;
        int idx = bb >> 5, c = bb & 31;
        int ns = idx ? 33 * idx + 1 : 0;
        #pragma unroll
        for (int uu = 0; uu < 2; uu++) {
            int e = t + uu * 256;
            int col = e >> 5, k = e & 31;
            int h = c * 32 + k;
            unsigned short v = 0;
            if (col < 2 && h < ns)
                v = f2bf(Wout[(size_t)(idx + col * 32) * H_ + permf(h)]);
            Wopk[(size_t)bb * 512 + e] = v;
        }
    } else {                            // biases
        int tt = (b - 1055) * 256 + t;  // over 3*1024
        int hp = tt & 1023;
        int p = permf(hp);
        if (tt < 1024) b0p[hp] = b0[p];
        else if (tt < 2048) bhp[hp] = bh[p];
        else bhp[1024 + hp] = bh[1024 + p];
    }
}

// ---- band K-partial: one wave, 16 slots x 8 rows (aliased to 16), chunks [c0,c1) ----
__device__ inline floatx4 band_partial(const unsigned short* act, const unsigned short* wpk,
                                       int aoff, int woff, int c0, int c1) {
    const unsigned short* ap = act + aoff;
    const unsigned short* wp = wpk + woff;
    floatx4 x = {0.f, 0.f, 0.f, 0.f}, y = {0.f, 0.f, 0.f, 0.f};
    int c = c0;
    for (; c + 1 < c1; c += 2) {
        short8 a0 = *(const short8*)(ap + c * ACH);
        short8 b0 = *(const short8*)(wp + (size_t)c * 2048);
        short8 a1 = *(const short8*)(ap + (c + 1) * ACH);
        short8 b1 = *(const short8*)(wp + (size_t)(c + 1) * 2048);
        x = __builtin_amdgcn_mfma_f32_16x16x32_bf16(a0, b0, x, 0, 0, 0);
        y = __builtin_amdgcn_mfma_f32_16x16x32_bf16(a1, b1, y, 0, 0, 0);
    }
    if (c < c1) {
        short8 a0 = *(const short8*)(ap + c * ACH);
        short8 b0 = *(const short8*)(wp + (size_t)c * 2048);
        x = __builtin_amdgcn_mfma_f32_16x16x32_bf16(a0, b0, x, 0, 0, 0);
    }
    return x + y;
}

// ---- mega-kernel: 512 wgs x 8 rows x 16 waves; 2 WGs/CU; full 32-step chain in LDS ----
__global__ __launch_bounds__(1024, 8) void mega_kernel(
        const float* __restrict__ z,
        const unsigned short* __restrict__ W0pk,
        const float* __restrict__ b0p,
        const unsigned short* __restrict__ Wpk,
        const float* __restrict__ bhp,
        const unsigned short* __restrict__ Wopk,
        const float* __restrict__ bout,
        float* __restrict__ xout) {
    __shared__ unsigned short aS[3 * 32 * ACH];    // a1,a2,a3 chunked [c][8 rows][40]
    __shared__ unsigned short xbS[RW * 32];        // running x, bf16
    __shared__ float xsS[RW * 32];                 // running x, fp32
    __shared__ float zsS[RW * 32];
    __shared__ floatx4 redS[12 * 64];              // K-split partials [q-1][s][lane]
    __shared__ float redO[16 * 32];                // out-dot partials [wave][col*16+m]

    const int tid = threadIdx.x;
    const int wave = tid >> 6, lane = tid & 63;
    const int frow = lane & 15, fk = lane >> 4;
    const int arow = (frow & 7) * ARW + fk * 8;    // A-frag offset (rows 8-15 alias 0-7)
    const int s = wave & 3, q = wave >> 2;
    const int m0 = blockIdx.x * RW;

    {   // zero-init LDS state (garbage x 0-weight must stay 0; matches x0 = 0)
        uint4 zz = {0u, 0u, 0u, 0u};
        for (int i = tid; i < 3 * 32 * ACH / 8; i += 1024) ((uint4*)aS)[i] = zz;
        if (tid < 32)  ((uint4*)xbS)[tid] = zz;
        if (tid < 64)  ((uint4*)xsS)[tid] = zz;
        if (tid < 128) ((uint4*)redO)[tid] = zz;
        if (tid < 64)  ((float4*)zsS)[tid] = ((const float4*)(z + (size_t)m0 * 32))[tid];
    }
    __syncthreads();

    unsigned short* a1 = aS;
    unsigned short* a2 = aS + 32 * ACH;
    unsigned short* a3 = aS + 64 * ACH;

    for (int idx = 0; idx < 32; idx++) {
        if (idx > 0) {
            const int nb0 = band0(idx);
            const int slot = nb0 + s * 16 + frow;
            const int nk = idx + 1;
            const int nk4 = (nk + 3) >> 2;
            const int c0 = q * nk4;
            const int c1 = (c0 + nk4 < nk) ? c0 + nk4 : nk;
            const unsigned short* wb2 = Wpk + (size_t)1024 * (idx - 1) * (idx + 2);
            const unsigned short* wb3 = wb2 + WPK_L;
            const int wsl = (slot >> 5) * ACH + (slot & 31);
            const int woff = s * 512 + frow * 32 + fk * 8;

            // layer 1 band (waves q==0): K=32 single chunk
            if (q == 0) {
                short8 a = *(const short8*)(xbS + (frow & 7) * 32 + fk * 8);
                short8 b = *(const short8*)(W0pk + (idx - 1) * 2048 + (s * 16 + frow) * 32 + fk * 8);
                floatx4 acc = {0.f, 0.f, 0.f, 0.f};
                acc = __builtin_amdgcn_mfma_f32_16x16x32_bf16(a, b, acc, 0, 0, 0);
                if (fk < 2) {
                    float bb = b0p[slot];
                    #pragma unroll
                    for (int r = 0; r < 4; r++)
                        a1[wsl + (fk * 4 + r) * ARW] = f2bf(fmaxf(acc[r] + bb, 0.f));
                }
            }
            __syncthreads();

            // layer 2 band: K-split partials + reduce
            {
                floatx4 p = band_partial(a1, wb2, arow, woff, c0, c1);
                if (q) redS[((q - 1) * 4 + s) * 64 + lane] = p;
                __syncthreads();
                if (q == 0) {
                    p = p + redS[s * 64 + lane] + redS[(4 + s) * 64 + lane]
                          + redS[(8 + s) * 64 + lane];
                    if (fk < 2) {
                        float bb = bhp[slot];
                        #pragma unroll
                        for (int r = 0; r < 4; r++)
                            a2[wsl + (fk * 4 + r) * ARW] = f2bf(fmaxf(p[r] + bb, 0.f));
                    }
                }
                __syncthreads();
            }

            // layer 3 band
            {
                floatx4 p = band_partial(a2, wb3, arow, woff, c0, c1);
                if (q) redS[((q - 1) * 4 + s) * 64 + lane] = p;
                __syncthreads();
                if (q == 0) {
                    p = p + redS[s * 64 + lane] + redS[(4 + s) * 64 + lane]
                          + redS[(8 + s) * 64 + lane];
                    if (fk < 2) {
                        float bb = bhp[H_ + slot];
                        #pragma unroll
                        for (int r = 0; r < 4; r++)
                            a3[wsl + (fk * 4 + r) * ARW] = f2bf(fmaxf(p[r] + bb, 0.f));
                    }
                }
                __syncthreads();
            }
        }

        // out-dot via MFMA: wave w covers live a3 chunks {2w, 2w+1} (chunk live iff c<=idx)
        if (wave * 2 <= idx) {
            floatx4 acc = {0.f, 0.f, 0.f, 0.f};
            #pragma unroll
            for (int cc = 0; cc < 2; cc++) {
                int c = wave * 2 + cc;
                if (c <= idx) {
                    short8 a = *(const short8*)(a3 + c * ACH + arow);
                    short8 b = *(const short8*)(Wopk + (size_t)((idx * 32 + c) * 16 + frow) * 32 + fk * 8);
                    acc = __builtin_amdgcn_mfma_f32_16x16x32_bf16(a, b, acc, 0, 0, 0);
                }
            }
            if (frow < 2 && fk < 2) {
                #pragma unroll
                for (int r = 0; r < 4; r++)
                    redO[wave * 32 + frow * 16 + fk * 4 + r] = acc[r];
            }
        }
        __syncthreads();
        if (tid < RW) {
            float sm = bout[idx], sl = bout[idx + D_];
            #pragma unroll
            for (int w = 0; w < 16; w++) {
                sm += redO[w * 32 + tid];
                sl += redO[w * 32 + 16 + tid];
            }
            float xi = fmaf(zsS[tid * 32 + idx], expf(sl), sm);
            xsS[tid * 32 + idx] = xi;
            xbS[tid * 32 + idx] = f2bf(xi);
        }
        __syncthreads();
    }

    if (tid < 64)
        ((float4*)(xout + (size_t)m0 * 32))[tid] = ((const float4*)xsS)[tid];
}

extern "C" void kernel_launch(void* const* d_in, const int* in_sizes, int n_in,
                              void* d_out, int out_size, void* d_ws, size_t ws_size,
                              hipStream_t stream) {
    const float* z    = (const float*)d_in[0];
    const float* W0   = (const float*)d_in[1];
    const float* b0   = (const float*)d_in[2];
    const float* Wh   = (const float*)d_in[3];   // [2, H, H]
    const float* bh   = (const float*)d_in[4];   // [2, H]
    const float* Wout = (const float*)d_in[5];   // [64, H]
    const float* bout = (const float*)d_in[6];   // [64]

    float* x = (float*)d_out;                          // [B, D] output
    unsigned short* Wpk  = (unsigned short*)d_ws;      // 2 * WPK_L
    unsigned short* W0pk = Wpk + 2 * WPK_L;            // 31 * 2048
    unsigned short* Wopk = W0pk + 31 * 2048;           // 32 * 32 * 512
    float* b0p = (float*)(Wopk + 32 * 32 * 512);       // [H]
    float* bhp = b0p + H_;                             // [2, H]

    pack_wh<<<2 * 31 * 32, 256, 0, stream>>>(Wh, Wpk);
    pack_misc<<<31 + 1024 + 12, 256, 0, stream>>>(W0, Wout, b0, bh, W0pk, Wopk, b0p, bhp);

    mega_kernel<<<B_ / RW, 1024, 0, stream>>>(z, W0pk, b0p, Wpk, bhp, Wopk, bout, x);
}

// Round 9
// 269.589 us; speedup vs baseline: 1.0429x; 1.0429x over previous
//
#include <hip/hip_runtime.h>
#include <hip/hip_bf16.h>

#define B_ 4096
#define D_ 32
#define H_ 1024
#define CS 512                 // activation chunk stride: [chunk][16 rows][32] shorts
#define WPK_L 1079296          // shorts per hidden-layer weight pack (= 2048*sum(idx+1))

typedef __attribute__((ext_vector_type(8))) short short8;
typedef __attribute__((ext_vector_type(4))) float floatx4;

__device__ inline unsigned short f2bf(float f) {      // fp32 -> bf16 bits, RNE
    unsigned u = __float_as_uint(f);
    unsigned r = (u + 0x7FFF + ((u >> 16) & 1)) >> 16;
    return (unsigned short)r;
}

// degree-sorted order: degree 0 -> slots [0,34), degree d>=1 -> slots [33d+1, 33d+34)
__device__ inline int degs(int hp) { return (hp < 34) ? 0 : (hp - 1) / 33; }
__device__ inline int permf(int hp) {                  // sorted slot -> original h
    int d = degs(hp);
    int r = d ? (hp - 33 * d - 1) : hp;
    return d + 31 * r;
}
__device__ inline int band0i(int idx) {                // fresh-band base slot at step idx>=1
    int nb0 = (idx == 1) ? 0 : 33 * idx - 32;
    return (nb0 > H_ - 64) ? H_ - 64 : nb0;
}

// ---- prep stage 1 (fused): permuted+masked Wbp, W0 packs, Wout packs, biases ----
__global__ __launch_bounds__(256) void prep1(
        const float* __restrict__ Wh, const float* __restrict__ W0,
        const float* __restrict__ Wout, const float* __restrict__ b0,
        const float* __restrict__ bh,
        unsigned short* __restrict__ Wbp, unsigned short* __restrict__ W0pk,
        unsigned short* __restrict__ Wopk, float* __restrict__ Woutp32,
        float* __restrict__ b0p, float* __restrict__ bhp) {
    __shared__ float row[H_];
    int b = blockIdx.x, t = threadIdx.x;
    if (b < 2048) {                          // Wbp[l][np][kp], staged via LDS (coalesced)
        int l = b >> 10, np = b & 1023;
        const float* src = Wh + ((size_t)l << 20) + ((size_t)permf(np) << 10);
        ((float4*)row)[t] = ((const float4*)src)[t];
        __syncthreads();
        int dn = degs(np);
        unsigned short o[4];
        #pragma unroll
        for (int j = 0; j < 4; j++) {
            int kp = t * 4 + j;
            o[j] = (dn >= degs(kp)) ? f2bf(row[permf(kp)]) : (unsigned short)0;
        }
        ((ushort4*)(Wbp + ((size_t)l << 20) + ((size_t)np << 10)))[t] =
            ushort4{o[0], o[1], o[2], o[3]};
    } else if (b < 2079) {                   // W0 band packs [idx][slot64][32]
        int idx = b - 2047;
        int nb0 = band0i(idx);
        int j = t >> 2, ko = (t & 3) * 8;
        int n = nb0 + j;
        int dn = degs(n);
        const float* srow = W0 + (size_t)permf(n) * 32;
        union { unsigned short o[8]; uint4 v; } u;
        #pragma unroll
        for (int e = 0; e < 8; e++)
            u.o[e] = (dn >= ko + e) ? f2bf(srow[ko + e]) : (unsigned short)0;
        *(uint4*)(W0pk + (idx - 1) * 2048 + j * 32 + ko) = u.v;
    } else if (b < 3103) {                   // Wout bf16 packs [idx][c][col16][32], h < band0
        int bb = b - 2079;
        int idx = bb >> 5, c = bb & 31;
        int limit = idx ? band0i(idx) : 0;   // finalized region only; fresh band via shuffle
        #pragma unroll
        for (int uu = 0; uu < 2; uu++) {
            int e = t + uu * 256;
            int col = e >> 5, k = e & 31;
            int h = c * 32 + k;
            unsigned short v = 0;
            if (col < 2 && h < limit)
                v = f2bf(Wout[(size_t)(idx + col * 32) * H_ + permf(h)]);
            Wopk[(size_t)bb * 512 + e] = v;
        }
    } else if (b < 3359) {                   // Woutp32 [64][1024] fp32, zero beyond prefix
        int tt = (b - 3103) * 256 + t;
        int r = tt >> 10, hp = tt & 1023;
        int m = r & 31;
        int ns = m ? 33 * m + 1 : 0;
        Woutp32[tt] = (hp < ns) ? Wout[(size_t)r * H_ + permf(hp)] : 0.f;
    } else {                                 // biases
        int tt = (b - 3359) * 256 + t;
        int hp = tt & 1023;
        int p = permf(hp);
        if (tt < 1024) b0p[hp] = b0[p];
        else if (tt < 2048) bhp[hp] = bh[p];
        else bhp[1024 + hp] = bh[1024 + p];
    }
}

// ---- prep stage 2: contiguous repack Wbp -> per-step band packs [c][slot64][32] ----
__global__ __launch_bounds__(256) void prep2(const unsigned short* __restrict__ Wbp,
                                             unsigned short* __restrict__ Wpk) {
    int b = blockIdx.x;                      // 2 layers * 31 idx * 32 chunks
    int l = b / 992;
    int r = b - l * 992;
    int idx = (r >> 5) + 1;
    int c = r & 31;
    if (c >= idx + 1) return;
    int nb0 = band0i(idx);
    int t = threadIdx.x;
    int j = t >> 2, ko = (t & 3) * 8;
    uint4 v = *(const uint4*)(Wbp + ((size_t)l << 20) + ((size_t)(nb0 + j) << 10) + c * 32 + ko);
    *(uint4*)(Wpk + (size_t)l * WPK_L + (size_t)1024 * (idx - 1) * (idx + 2)
              + c * 2048 + j * 32 + ko) = v;
}

// ---- band K-partial with prefetched weights ----
__device__ inline floatx4 band_pf(const unsigned short* act, const short8* w,
                                  int arow, int c0, int c1) {
    floatx4 x = {0.f, 0.f, 0.f, 0.f}, y = {0.f, 0.f, 0.f, 0.f};
    #pragma unroll
    for (int u = 0; u < 8; u += 2) {
        if (c0 + u < c1) {
            short8 a = *(const short8*)(act + (c0 + u) * CS + arow);
            x = __builtin_amdgcn_mfma_f32_16x16x32_bf16(a, w[u], x, 0, 0, 0);
        }
        if (c0 + u + 1 < c1) {
            short8 a = *(const short8*)(act + (c0 + u + 1) * CS + arow);
            y = __builtin_amdgcn_mfma_f32_16x16x32_bf16(a, w[u + 1], y, 0, 0, 0);
        }
    }
    return x + y;
}

// ---- mega-kernel: 256 wgs x 16 rows x 16 waves; 32-step chain in LDS ----
__global__ __launch_bounds__(1024) void mega_kernel(
        const float* __restrict__ z,
        const unsigned short* __restrict__ W0pk,
        const float* __restrict__ b0p,
        const unsigned short* __restrict__ Wpk,
        const float* __restrict__ bhp,
        const unsigned short* __restrict__ Wopk,
        const float* __restrict__ Woutp32,
        const float* __restrict__ bout,
        float* __restrict__ xout) {
    __shared__ unsigned short aS[3 * 32 * CS];     // a1,a2,a3: [c][16 rows][32], 32KB each
    __shared__ unsigned short xbS[16 * 32];        // running x, bf16
    __shared__ float xsS[512];                     // running x, fp32
    __shared__ float zsS[512];
    __shared__ floatx4 redS[12 * 64];              // K-split partials [q-1][s][lane]
    __shared__ float redO[16 * 32];                // old out-dot partials [wave][col*16+m]
    __shared__ float redF[4 * 32];                 // fresh out-dot partials [s][col*16+m]

    const int tid = threadIdx.x;
    const int wave = tid >> 6, lane = tid & 63;
    const int frow = lane & 15, fk = lane >> 4;
    const int arow = frow * 32 + fk * 8;
    const int s = wave & 3, q = wave >> 2;
    const int m0 = blockIdx.x * 16;

    {   // zero-init (garbage x 0-weight must stay 0; matches x0 = 0)
        uint4 zz = {0u, 0u, 0u, 0u};
        for (int i = tid; i < 3 * 32 * CS / 8; i += 1024) ((uint4*)aS)[i] = zz;
        if (tid < 64)  ((uint4*)xbS)[tid] = zz;
        if (tid < 128) ((uint4*)xsS)[tid] = zz;
        if (tid < 128) ((uint4*)redO)[tid] = zz;
        if (tid < 32)  ((uint4*)redF)[tid] = zz;
        if (tid < 128) ((float4*)zsS)[tid] = ((const float4*)(z + (size_t)m0 * 32))[tid];
    }
    __syncthreads();

    unsigned short* a1 = aS;
    unsigned short* a2 = aS + 32 * CS;
    unsigned short* a3 = aS + 64 * CS;

    for (int idx = 0; idx < 32; idx++) {
        const int nb0 = (idx > 0) ? band0i(idx) : 0;
        const int cf  = (idx > 0) ? (nb0 >> 5) : 0;   // boundary chunk of finalized region
        const int nk = idx + 1;
        const int nk4 = (nk + 3) >> 2;
        const int c0 = q * nk4;
        const int c1m = (c0 + nk4 < nk) ? c0 + nk4 : nk;
        const int slot = nb0 + s * 16 + frow;
        const int wsl = (slot >> 5) * CS + (slot & 31);

        // ---- step-top weight prefetch (single load-latency exposure per step) ----
        short8 wA[8], wB[8];
        if (idx > 0) {
            const unsigned short* wb2 = Wpk + (size_t)1024 * (idx - 1) * (idx + 2);
            const unsigned short* wb3 = wb2 + WPK_L;
            const int woff = s * 512 + frow * 32 + fk * 8;
            #pragma unroll
            for (int u = 0; u < 8; u++) {
                int cc = c0 + u; if (cc > nk - 1) cc = nk - 1;   // clamp: stay in-pack
                wA[u] = *(const short8*)(wb2 + (size_t)cc * 2048 + woff);
                wB[u] = *(const short8*)(wb3 + (size_t)cc * 2048 + woff);
            }
        }

        // ---- step-top out-dot over finalized a3 chunks (c <= cf; Wopk boundary-masked) ----
        {
            const int ca = wave * 2, cb = ca + 1;
            if (ca <= cf) {
                floatx4 oacc = {0.f, 0.f, 0.f, 0.f};
                short8 a = *(const short8*)(a3 + ca * CS + arow);
                short8 bf = *(const short8*)(Wopk + (size_t)((idx * 32 + ca) * 16 + frow) * 32 + fk * 8);
                oacc = __builtin_amdgcn_mfma_f32_16x16x32_bf16(a, bf, oacc, 0, 0, 0);
                if (cb <= cf) {
                    a = *(const short8*)(a3 + cb * CS + arow);
                    bf = *(const short8*)(Wopk + (size_t)((idx * 32 + cb) * 16 + frow) * 32 + fk * 8);
                    oacc = __builtin_amdgcn_mfma_f32_16x16x32_bf16(a, bf, oacc, 0, 0, 0);
                }
                if (frow < 2) {
                    #pragma unroll
                    for (int r = 0; r < 4; r++)
                        redO[wave * 32 + frow * 16 + fk * 4 + r] = oacc[r];
                }
            }
        }

        if (idx > 0) {
            // ---- layer 1 band (q==0): K=32 single chunk ----
            if (q == 0) {
                short8 a = *(const short8*)(xbS + frow * 32 + fk * 8);
                short8 bf = *(const short8*)(W0pk + (idx - 1) * 2048 + (s * 16 + frow) * 32 + fk * 8);
                floatx4 acc = {0.f, 0.f, 0.f, 0.f};
                acc = __builtin_amdgcn_mfma_f32_16x16x32_bf16(a, bf, acc, 0, 0, 0);
                float bb = b0p[slot];
                #pragma unroll
                for (int r = 0; r < 4; r++)
                    a1[wsl + (fk * 4 + r) * 32] = f2bf(fmaxf(acc[r] + bb, 0.f));
            }
            __syncthreads();                                   // A: a1 visible

            // ---- layer 2 band ----
            {
                floatx4 p = band_pf(a1, wA, arow, c0, c1m);
                if (q) redS[((q - 1) * 4 + s) * 64 + lane] = p;
                __syncthreads();                               // B: partials visible
                if (q == 0) {
                    p = p + redS[s * 64 + lane] + redS[(4 + s) * 64 + lane]
                          + redS[(8 + s) * 64 + lane];
                    float bb = bhp[slot];
                    #pragma unroll
                    for (int r = 0; r < 4; r++)
                        a2[wsl + (fk * 4 + r) * 32] = f2bf(fmaxf(p[r] + bb, 0.f));
                }
                __syncthreads();                               // C: a2 visible
            }

            // ---- layer 3 band + fused fresh out-dot (register shuffle, no extra barrier) ----
            {
                floatx4 p = band_pf(a2, wB, arow, c0, c1m);
                if (q) redS[((q - 1) * 4 + s) * 64 + lane] = p;
                __syncthreads();                               // D: partials visible
                if (q == 0) {
                    p = p + redS[s * 64 + lane] + redS[(4 + s) * 64 + lane]
                          + redS[(8 + s) * 64 + lane];
                    float bb = bhp[H_ + slot];
                    float v[4];
                    #pragma unroll
                    for (int r = 0; r < 4; r++) {
                        v[r] = fmaxf(p[r] + bb, 0.f);
                        a3[wsl + (fk * 4 + r) * 32] = f2bf(v[r]);
                    }
                    float wmu = Woutp32[(size_t)idx * H_ + slot];        // zero beyond prefix
                    float wls = Woutp32[(size_t)(idx + D_) * H_ + slot];
                    float pm[4], pl[4];
                    #pragma unroll
                    for (int r = 0; r < 4; r++) { pm[r] = v[r] * wmu; pl[r] = v[r] * wls; }
                    #pragma unroll
                    for (int off = 1; off < 16; off <<= 1) {
                        #pragma unroll
                        for (int r = 0; r < 4; r++) {
                            pm[r] += __shfl_xor(pm[r], off);
                            pl[r] += __shfl_xor(pl[r], off);
                        }
                    }
                    if (frow == 0) {
                        #pragma unroll
                        for (int r = 0; r < 4; r++) {
                            redF[s * 32 + fk * 4 + r]      = pm[r];
                            redF[s * 32 + 16 + fk * 4 + r] = pl[r];
                        }
                    }
                }
            }
        }
        __syncthreads();                                       // F: redO/redF visible
        if (tid < 16) {
            float sm = bout[idx], sl = bout[idx + D_];
            #pragma unroll
            for (int w = 0; w < 16; w++) {
                sm += redO[w * 32 + tid];
                sl += redO[w * 32 + 16 + tid];
            }
            #pragma unroll
            for (int t4 = 0; t4 < 4; t4++) {
                sm += redF[t4 * 32 + tid];
                sl += redF[t4 * 32 + 16 + tid];
            }
            float xi = fmaf(zsS[tid * 32 + idx], expf(sl), sm);
            xsS[tid * 32 + idx] = xi;
            xbS[tid * 32 + idx] = f2bf(xi);
        }
        __syncthreads();                                       // G: x visible for next step
    }

    if (tid < 128)
        ((float4*)(xout + (size_t)m0 * 32))[tid] = ((const float4*)xsS)[tid];
}

extern "C" void kernel_launch(void* const* d_in, const int* in_sizes, int n_in,
                              void* d_out, int out_size, void* d_ws, size_t ws_size,
                              hipStream_t stream) {
    const float* z    = (const float*)d_in[0];
    const float* W0   = (const float*)d_in[1];
    const float* b0   = (const float*)d_in[2];
    const float* Wh   = (const float*)d_in[3];   // [2, H, H]
    const float* bh   = (const float*)d_in[4];   // [2, H]
    const float* Wout = (const float*)d_in[5];   // [64, H]
    const float* bout = (const float*)d_in[6];   // [64]

    float* x = (float*)d_out;                          // [B, D] output
    unsigned short* Wbp   = (unsigned short*)d_ws;     // [2, H, H] permuted+masked bf16
    unsigned short* Wpk   = Wbp + 2 * H_ * H_;         // 2 * WPK_L band packs
    unsigned short* W0pk  = Wpk + 2 * WPK_L;           // 31 * 2048
    unsigned short* Wopk  = W0pk + 31 * 2048;          // 32 * 32 * 512
    float* Woutp32 = (float*)(Wopk + 32 * 32 * 512);   // [64, 1024] fp32 permuted
    float* b0p = Woutp32 + 64 * H_;                    // [H]
    float* bhp = b0p + H_;                             // [2, H]

    prep1<<<3371, 256, 0, stream>>>(Wh, W0, Wout, b0, bh, Wbp, W0pk, Wopk, Woutp32, b0p, bhp);
    prep2<<<2 * 31 * 32, 256, 0, stream>>>(Wbp, Wpk);

    mega_kernel<<<B_ / 16, 1024, 0, stream>>>(z, W0pk, b0p, Wpk, bhp, Wopk, Woutp32, bout, x);
}